// Round 13
// baseline (5970.618 us; speedup 1.0000x reference)
//
#include <hip/hip_runtime.h>
#include <stdint.h>

#define NB 256      // batch
#define TSEQ 1024   // sequence length
#define TT_MAX 64

// W_hh per-row split (128 f16-pairs per gate row): 20 reg + 48 LDS + 60 stream
#define REG_P 20
#define LDS_P 48
#define STR_P 60
#define LDSTR 148   // u32 stride of per-thread LDS slice (3*48=144 + pad; 592B ≡ 80B mod 128 -> 0-conflict, proven R12)

typedef _Float16 f16;
typedef _Float16 h2 __attribute__((ext_vector_type(2)));

static __device__ __forceinline__ uint32_t pkh2(float a, float b) {
  h2 v; v[0] = (f16)a; v[1] = (f16)b;
  return __builtin_bit_cast(uint32_t, v);
}

#if __has_builtin(__builtin_amdgcn_fdot2)
static __device__ __forceinline__ float dot2u(uint32_t w, uint32_t h, float c) {
  return __builtin_amdgcn_fdot2(__builtin_bit_cast(h2, w), __builtin_bit_cast(h2, h), c, false);
}
#else
static __device__ __forceinline__ float dot2u(uint32_t w, uint32_t h, float c) {
  h2 a = __builtin_bit_cast(h2, w), b = __builtin_bit_cast(h2, h);
  return c + (float)a[0] * (float)b[0] + (float)a[1] * (float)b[1];
}
#endif

#if __has_builtin(__builtin_amdgcn_rcpf)
#define RCPF(x) __builtin_amdgcn_rcpf(x)
#else
#define RCPF(x) (1.0f / (x))
#endif

static __device__ __forceinline__ float sigm(float x) {
  return RCPF(1.0f + exp2f(-1.44269504f * x));
}
static __device__ __forceinline__ float tanh_f(float x) {
  return 1.0f - 2.0f * RCPF(1.0f + exp2f(2.88539008f * x));
}

// ---------------------------------------------------------------------------
// One-time weight pack (f16). Thread t owns gate rows (t, t+256, t+512).
//  whr : reg part,    [(rr*5  + p/4)*256 + t] uint4, pairs [0,20)
//  whl : LDS part,    [t*LDSTR + rr*48 + p],        pairs [20,68)
//  whs : stream part, [(rr*15 + p/4)*256 + t] uint4, pairs [68,128)
//  whz : W_ih z-cols, [(rr*4  + p/4)*256 + t] uint4, 16 pairs
//  wep : enc h-part,  [(p/4)*256 + t] uint4 — thread t holds enc row e=t&63,
//        pairs pc = (t>>6)*32 + p, p<32  (wave-uniform h broadcast in phase A)
// ---------------------------------------------------------------------------
__global__ __launch_bounds__(256) void vrnn_pack(
    const float* __restrict__ W_hh, const float* __restrict__ W_ih,
    const float* __restrict__ emW, const float* __restrict__ esW,
    uint32_t* __restrict__ whr, uint32_t* __restrict__ whl,
    uint32_t* __restrict__ whs, uint32_t* __restrict__ whz,
    uint32_t* __restrict__ wep)
{
  const int t = threadIdx.x;
  for (int rr = 0; rr < 3; ++rr) {
    const float* R = W_hh + (size_t)(t + rr * 256) * 256;
    for (int p = 0; p < REG_P; ++p)
      whr[(((size_t)rr * 5 + (p >> 2)) * 256 + t) * 4 + (p & 3)] = pkh2(R[2 * p], R[2 * p + 1]);
    for (int p = 0; p < LDS_P; ++p)
      whl[(size_t)t * LDSTR + rr * LDS_P + p] = pkh2(R[2 * (p + REG_P)], R[2 * (p + REG_P) + 1]);
    for (int p = 0; p < STR_P; ++p)
      whs[(((size_t)rr * 15 + (p >> 2)) * 256 + t) * 4 + (p & 3)] =
          pkh2(R[2 * (p + REG_P + LDS_P)], R[2 * (p + REG_P + LDS_P) + 1]);
    const float* Z = W_ih + (size_t)(t + rr * 256) * 96 + 64;
    for (int p = 0; p < 16; ++p)
      whz[(((size_t)rr * 4 + (p >> 2)) * 256 + t) * 4 + (p & 3)] = pkh2(Z[2 * p], Z[2 * p + 1]);
  }
  const int e = t & 63, s = t >> 6;
  const float* src = (e < 32) ? (emW + (size_t)e * 320 + 64)
                              : (esW + (size_t)(e - 32) * 320 + 64);
  for (int p = 0; p < 32; ++p) {
    int pc = s * 32 + p;
    wep[(((size_t)(p >> 2)) * 256 + t) * 4 + (p & 3)] = pkh2(src[2 * pc], src[2 * pc + 1]);
  }
}

// ---------------------------------------------------------------------------
// Precompute kernel (unchanged): gi_x'[t][b][768], zx'[t][b][64]
// ---------------------------------------------------------------------------
__global__ __launch_bounds__(256, 2) void vrnn_pre(
    const float* __restrict__ x, const float* __restrict__ W_ih,
    const float* __restrict__ b_ih, const float* __restrict__ b_hh,
    const float* __restrict__ emW, const float* __restrict__ emb,
    const float* __restrict__ esW, const float* __restrict__ esb,
    f16* __restrict__ gix, f16* __restrict__ zx,
    int chunk_t0, int TT, int nTT)
{
  const int tid = threadIdx.x;
  const int b  = blockIdx.x / nTT;
  const int tt = blockIdx.x % nTT;
  const int tloc0 = tt * TT;

  uint32_t wx[3][32];
  float bias[3];
  #pragma unroll
  for (int rr = 0; rr < 3; ++rr) {
    int j = tid + rr * 256;
    const float4* wr = (const float4*)(W_ih + (size_t)j * 96);
    #pragma unroll
    for (int p4 = 0; p4 < 16; ++p4) {
      float4 v = wr[p4];
      wx[rr][2 * p4]     = pkh2(v.x, v.y);
      wx[rr][2 * p4 + 1] = pkh2(v.z, v.w);
    }
    bias[rr] = b_ih[j] + (rr < 2 ? b_hh[j] : 0.0f);  // fold b_hh into r,z rows only
  }
  uint32_t we[32]; float ebias = 0.0f;
  if (tid < 64) {
    const float* src = (tid < 32) ? (emW + (size_t)tid * 320)
                                  : (esW + (size_t)(tid - 32) * 320);
    #pragma unroll
    for (int p = 0; p < 32; ++p) we[p] = pkh2(src[2 * p], src[2 * p + 1]);
    ebias = (tid < 32) ? emb[tid] : esb[tid - 32];
  }

  __shared__ uint32_t xs[TT_MAX * 32];
  for (int idx = tid; idx < TT * 32; idx += 256) {
    int tl = idx >> 5, pk = idx & 31;
    size_t base = ((size_t)b * TSEQ + (chunk_t0 + tloc0 + tl)) * 64 + 2 * pk;
    xs[idx] = pkh2(x[base], x[base + 1]);
  }
  __syncthreads();

  for (int tl = 0; tl < TT; ++tl) {
    float a0 = bias[0], a1 = bias[1], a2 = bias[2];
    #pragma unroll
    for (int p = 0; p < 32; ++p) {
      uint32_t u = xs[tl * 32 + p];
      a0 = dot2u(wx[0][p], u, a0);
      a1 = dot2u(wx[1][p], u, a1);
      a2 = dot2u(wx[2][p], u, a2);
    }
    size_t ob = (size_t)(tloc0 + tl) * NB + b;
    f16* g = gix + ob * 768;
    g[tid] = (f16)a0; g[tid + 256] = (f16)a1; g[tid + 512] = (f16)a2;
    if (tid < 64) {
      float a3 = ebias;
      #pragma unroll
      for (int p = 0; p < 32; ++p) a3 = dot2u(we[p], xs[tl * 32 + p], a3);
      zx[ob * 64 + tid] = (f16)a3;
    }
  }
}

// ---------------------------------------------------------------------------
// Recurrent kernel v6: 256 threads, one block per TWO batch elements (grid 128).
// R12 post-mortem: correct & spill-free but 1 wave/SIMD left VALUBusy at 28% —
// all LDS/L2 latency and barrier cost exposed. Two independent batch elements
// per block fill the idle issue slots (ILP), share the register/LDS weights,
// and halve the per-XCD L2 weight-stream demand (weights loaded once, dotted
// twice). encoder weights moved LDS->regs (wave-uniform h broadcasts), W_hh
// LDS share raised to 48 pairs/row, stream 60 pairs/row.
// ---------------------------------------------------------------------------
__global__ __launch_bounds__(256, 2) void vrnn_rec(
    const f16* __restrict__ gix, const f16* __restrict__ zx,
    const float* __restrict__ eps,
    const uint32_t* __restrict__ whr, const uint32_t* __restrict__ whl_g,
    const uint32_t* __restrict__ whs, const uint32_t* __restrict__ whz,
    const uint32_t* __restrict__ wep_g,
    const float* __restrict__ b_hh,
    float* __restrict__ hws, float* __restrict__ out,
    int t0, int Tlen, int first, int last)
{
  const int t  = threadIdx.x;
  const int b0 = 2 * blockIdx.x, b1 = b0 + 1;

  // ---- pinned register weights ----
  uint32_t wrg[3][REG_P];              // 60
  {
    const uint4* w4 = (const uint4*)whr;
    #pragma unroll
    for (int c = 0; c < 15; ++c) {
      uint4 v = w4[c * 256 + t];
      int rr = c / 5, p4 = c % 5;
      wrg[rr][4 * p4] = v.x; wrg[rr][4 * p4 + 1] = v.y;
      wrg[rr][4 * p4 + 2] = v.z; wrg[rr][4 * p4 + 3] = v.w;
    }
  }
  uint32_t wz[3][16];                  // 48
  {
    const uint4* w4 = (const uint4*)whz;
    #pragma unroll
    for (int c = 0; c < 12; ++c) {
      uint4 v = w4[c * 256 + t];
      int rr = c / 4, p4 = c % 4;
      wz[rr][4 * p4] = v.x; wz[rr][4 * p4 + 1] = v.y;
      wz[rr][4 * p4 + 2] = v.z; wz[rr][4 * p4 + 3] = v.w;
    }
  }
  uint32_t we[32];                     // 32
  {
    const uint4* w4 = (const uint4*)wep_g;
    #pragma unroll
    for (int c = 0; c < 8; ++c) {
      uint4 v = w4[c * 256 + t];
      we[4 * c] = v.x; we[4 * c + 1] = v.y; we[4 * c + 2] = v.z; we[4 * c + 3] = v.w;
    }
  }
  #pragma unroll
  for (int rr = 0; rr < 3; ++rr) {
    #pragma unroll
    for (int i = 0; i < REG_P; ++i) asm volatile("" : "+v"(wrg[rr][i]));
    #pragma unroll
    for (int i = 0; i < 16; ++i)   asm volatile("" : "+v"(wz[rr][i]));
  }
  #pragma unroll
  for (int i = 0; i < 32; ++i) asm volatile("" : "+v"(we[i]));
  const float bhn = b_hh[512 + t];

  // ---- LDS (~156 KB) ----
  __shared__ uint32_t lwh[256 * LDSTR];          // 151,552 B
  __shared__ __align__(16) f16 hf0[2][256];
  __shared__ __align__(16) f16 hf1[2][256];
  __shared__ float encp0[256], encp1[256];
  __shared__ uint32_t zu0[16], zu1[16];

  {
    const uint4* src = (const uint4*)(whl_g + (size_t)t * LDSTR);
    uint4* dst = (uint4*)(lwh + (size_t)t * LDSTR);
    #pragma unroll
    for (int j = 0; j < LDSTR / 4; ++j) dst[j] = src[j];
  }

  float hm0 = first ? 0.0f : hws[b0 * 256 + t];
  float hm1 = first ? 0.0f : hws[b1 * 256 + t];
  hf0[0][t] = (f16)hm0;
  hf1[0][t] = (f16)hm1;
  __syncthreads();

  // ---- stream prefetch for t=0 ----
  const f16* gp0 = gix + (size_t)b0 * 768;
  const f16* gp1 = gix + (size_t)b1 * 768;
  float pf00 = (float)gp0[t], pf01 = (float)gp0[t + 256], pf02 = (float)gp0[t + 512];
  float pf10 = (float)gp1[t], pf11 = (float)gp1[t + 256], pf12 = (float)gp1[t + 512];
  const int rowz = t & 31;
  const int bz   = (t < 32) ? b0 : b1;     // lanes 0-31: b0, 32-63: b1 (wave 0 only)
  float pf_zm = 0.0f, pf_zl = 0.0f, pf_ep = 0.0f;
  if (t < 64) {
    const f16* zp = zx + (size_t)bz * 64;
    pf_zm = (float)zp[rowz]; pf_zl = (float)zp[32 + rowz];
    pf_ep = eps[((size_t)t0 * NB + bz) * 32 + rowz];
  }

  const int s = t >> 6;                      // wave id (phase-A k-slice)
  const uint32_t* myl = lwh + (size_t)t * LDSTR;
  const uint4* whs4 = (const uint4*)whs;

  for (int tl = 0; tl < Tlen; ++tl) {
    const int cur = tl & 1, nxt = cur ^ 1;
    const uint32_t* hu0 = (const uint32_t*)&hf0[cur][0];
    const uint32_t* hu1 = (const uint32_t*)&hf1[cur][0];
    const uint4* hu40 = (const uint4*)hu0;
    const uint4* hu41 = (const uint4*)hu1;

    // ---- phase A: encoder partials, both batches (wave-uniform h broadcast) ----
    float ep0 = 0.0f, ep1 = 0.0f;
    #pragma unroll
    for (int p = 0; p < 32; ++p) {
      int pc = s * 32 + p;
      uint32_t u0 = hu0[pc], u1 = hu1[pc];
      ep0 = dot2u(we[p], u0, ep0);
      ep1 = dot2u(we[p], u1, ep1);
    }
    encp0[t] = ep0; encp1[t] = ep1;
    __syncthreads();  // b1

    // ---- phase B: z finalize (wave 0, 64 lanes) || gh (all threads) ----
    if (t < 64) {
      const float* ep = (t < 32) ? encp0 : encp1;
      float mu = pf_zm, lv = pf_zl;
      #pragma unroll
      for (int ss = 0; ss < 4; ++ss) {
        mu += ep[ss * 64 + rowz];
        lv += ep[ss * 64 + 32 + rowz];
      }
      float z = mu + pf_ep * exp2f(0.72134752f * lv);   // mu + eps*exp(0.5*lv)
      f16* zz = (t < 32) ? (f16*)zu0 : (f16*)zu1;
      zz[rowz] = (f16)z;
    }
    float g00 = 0.0f, g01 = 0.0f, g02 = 0.0f;   // b0: r,u,n (pure W_hh@h)
    float g10 = 0.0f, g11 = 0.0f, g12 = 0.0f;   // b1
    // pairs [0,20): register weights
    #pragma unroll
    for (int g4 = 0; g4 < 5; ++g4) {
      uint4 u40 = hu40[g4], u41 = hu41[g4];
      #pragma unroll
      for (int i = 0; i < 4; ++i) {
        uint32_t uc0 = (i == 0) ? u40.x : (i == 1) ? u40.y : (i == 2) ? u40.z : u40.w;
        uint32_t uc1 = (i == 0) ? u41.x : (i == 1) ? u41.y : (i == 2) ? u41.z : u41.w;
        uint32_t w0 = wrg[0][4 * g4 + i], w1 = wrg[1][4 * g4 + i], w2 = wrg[2][4 * g4 + i];
        g00 = dot2u(w0, uc0, g00); g01 = dot2u(w1, uc0, g01); g02 = dot2u(w2, uc0, g02);
        g10 = dot2u(w0, uc1, g10); g11 = dot2u(w1, uc1, g11); g12 = dot2u(w2, uc1, g12);
      }
    }
    // pairs [20,68): LDS own slice (weights read once, dotted twice)
    #pragma unroll
    for (int g4 = 0; g4 < 12; ++g4) {
      uint4 u40 = hu40[5 + g4], u41 = hu41[5 + g4];
      uint4 w0 = *(const uint4*)(myl + 0 * LDS_P + 4 * g4);
      uint4 w1 = *(const uint4*)(myl + 1 * LDS_P + 4 * g4);
      uint4 w2 = *(const uint4*)(myl + 2 * LDS_P + 4 * g4);
      g00 = dot2u(w0.x, u40.x, g00); g01 = dot2u(w1.x, u40.x, g01); g02 = dot2u(w2.x, u40.x, g02);
      g10 = dot2u(w0.x, u41.x, g10); g11 = dot2u(w1.x, u41.x, g11); g12 = dot2u(w2.x, u41.x, g12);
      g00 = dot2u(w0.y, u40.y, g00); g01 = dot2u(w1.y, u40.y, g01); g02 = dot2u(w2.y, u40.y, g02);
      g10 = dot2u(w0.y, u41.y, g10); g11 = dot2u(w1.y, u41.y, g11); g12 = dot2u(w2.y, u41.y, g12);
      g00 = dot2u(w0.z, u40.z, g00); g01 = dot2u(w1.z, u40.z, g01); g02 = dot2u(w2.z, u40.z, g02);
      g10 = dot2u(w0.z, u41.z, g10); g11 = dot2u(w1.z, u41.z, g11); g12 = dot2u(w2.z, u41.z, g12);
      g00 = dot2u(w0.w, u40.w, g00); g01 = dot2u(w1.w, u40.w, g01); g02 = dot2u(w2.w, u40.w, g02);
      g10 = dot2u(w0.w, u41.w, g10); g11 = dot2u(w1.w, u41.w, g11); g12 = dot2u(w2.w, u41.w, g12);
    }
    // pairs [68,128): streamed from shared L2-resident region; load once, dot twice
    #pragma unroll
    for (int rr = 0; rr < 3; ++rr) {
      uint4 sbuf[15];
      #pragma unroll
      for (int j = 0; j < 15; ++j) sbuf[j] = whs4[(rr * 15 + j) * 256 + t];
      float a0 = 0.0f, a1 = 0.0f;
      #pragma unroll
      for (int j = 0; j < 15; ++j) {
        uint4 u40 = hu40[17 + j], u41 = hu41[17 + j];
        a0 = dot2u(sbuf[j].x, u40.x, a0); a1 = dot2u(sbuf[j].x, u41.x, a1);
        a0 = dot2u(sbuf[j].y, u40.y, a0); a1 = dot2u(sbuf[j].y, u41.y, a1);
        a0 = dot2u(sbuf[j].z, u40.z, a0); a1 = dot2u(sbuf[j].z, u41.z, a1);
        a0 = dot2u(sbuf[j].w, u40.w, a0); a1 = dot2u(sbuf[j].w, u41.w, a1);
      }
      if      (rr == 0) { g00 += a0; g10 += a1; }
      else if (rr == 1) { g01 += a0; g11 += a1; }
      else              { g02 += a0; g12 += a1; }
    }
    __syncthreads();  // b2  (zu visible)

    // ---- phase C: gi_z from broadcast z, gates, both batches ----
    float q00 = 0.0f, q01 = 0.0f, q02 = 0.0f;
    float q10 = 0.0f, q11 = 0.0f, q12 = 0.0f;
    #pragma unroll
    for (int p = 0; p < 16; ++p) {
      uint32_t u0 = zu0[p], u1 = zu1[p];          // broadcast reads
      q00 = dot2u(wz[0][p], u0, q00); q01 = dot2u(wz[1][p], u0, q01); q02 = dot2u(wz[2][p], u0, q02);
      q10 = dot2u(wz[0][p], u1, q10); q11 = dot2u(wz[1][p], u1, q11); q12 = dot2u(wz[2][p], u1, q12);
    }
    {
      float r  = sigm(pf00 + g00 + q00);
      float uu = sigm(pf01 + g01 + q01);
      float n  = tanh_f(pf02 + q02 + r * (g02 + bhn));
      hm0 = (1.0f - uu) * n + uu * hm0;
      hf0[nxt][t] = (f16)hm0;
    }
    {
      float r  = sigm(pf10 + g10 + q10);
      float uu = sigm(pf11 + g11 + q11);
      float n  = tanh_f(pf12 + q12 + r * (g12 + bhn));
      hm1 = (1.0f - uu) * n + uu * hm1;
      hf1[nxt][t] = (f16)hm1;
    }

    // ---- prefetch streams for tl+1 ----
    int tn = (tl + 1 < Tlen) ? tl + 1 : tl;
    const f16* g0p = gix + ((size_t)tn * NB + b0) * 768;
    const f16* g1p = gix + ((size_t)tn * NB + b1) * 768;
    pf00 = (float)g0p[t]; pf01 = (float)g0p[t + 256]; pf02 = (float)g0p[t + 512];
    pf10 = (float)g1p[t]; pf11 = (float)g1p[t + 256]; pf12 = (float)g1p[t + 512];
    if (t < 64) {
      const f16* zp = zx + ((size_t)tn * NB + bz) * 64;
      pf_zm = (float)zp[rowz]; pf_zl = (float)zp[32 + rowz];
      pf_ep = eps[((size_t)(t0 + tn) * NB + bz) * 32 + rowz];
    }
    __syncthreads();  // b3  (h_new visible)
  }

  if (last) { out[b0 * 256 + t] = hm0; out[b1 * 256 + t] = hm1; }
  else      { hws[b0 * 256 + t] = hm0; hws[b1 * 256 + t] = hm1; }
}

extern "C" void kernel_launch(void* const* d_in, const int* in_sizes, int n_in,
                              void* d_out, int out_size, void* d_ws, size_t ws_size,
                              hipStream_t stream) {
  const float* x    = (const float*)d_in[0];
  const float* eps  = (const float*)d_in[1];
  const float* emW  = (const float*)d_in[2];
  const float* emb  = (const float*)d_in[3];
  const float* esW  = (const float*)d_in[4];
  const float* esb  = (const float*)d_in[5];
  const float* W_ih = (const float*)d_in[10];
  const float* W_hh = (const float*)d_in[11];
  const float* b_ih = (const float*)d_in[12];
  const float* b_hh = (const float*)d_in[13];
  float* out = (float*)d_out;

  // workspace layout (16B-aligned regions)
  const size_t o_whr = 262144;                  // hws: 256 KB
  const size_t o_whl = o_whr + 61440;           // whr: 15*256*16
  const size_t o_whs = o_whl + 151552;          // whl: 148*256*4
  const size_t o_whz = o_whs + 184320;          // whs: 45*256*16
  const size_t o_wep = o_whz + 49152;           // whz: 12*256*16
  const size_t o_gix = o_wep + 32768;           // wep: 8*256*16  -> 741,376
  int Tc = TSEQ;
  while (Tc > 8 && o_gix + (size_t)Tc * NB * (768 + 64) * 2 > ws_size) Tc >>= 1;

  float*    hws   = (float*)d_ws;
  uint32_t* whr   = (uint32_t*)((char*)d_ws + o_whr);
  uint32_t* whl_g = (uint32_t*)((char*)d_ws + o_whl);
  uint32_t* whs   = (uint32_t*)((char*)d_ws + o_whs);
  uint32_t* whz   = (uint32_t*)((char*)d_ws + o_whz);
  uint32_t* wep   = (uint32_t*)((char*)d_ws + o_wep);
  f16*      gix   = (f16*)((char*)d_ws + o_gix);
  f16*      zx    = gix + (size_t)Tc * NB * 768;

  vrnn_pack<<<dim3(1), dim3(256), 0, stream>>>(W_hh, W_ih, emW, esW,
                                               whr, whl_g, whs, whz, wep);

  int nch = TSEQ / Tc;
  int TT  = Tc < 64 ? Tc : 64;
  int nTT = Tc / TT;

  for (int c = 0; c < nch; ++c) {
    vrnn_pre<<<dim3(NB * nTT), dim3(256), 0, stream>>>(
        x, W_ih, b_ih, b_hh, emW, emb, esW, esb, gix, zx, c * Tc, TT, nTT);
    vrnn_rec<<<dim3(NB / 2), dim3(256), 0, stream>>>(
        gix, zx, eps, whr, whl_g, whs, whz, wep, b_hh, hws, out,
        c * Tc, Tc, c == 0 ? 1 : 0, c == nch - 1 ? 1 : 0);
  }
}

// Round 14
// 2974.731 us; speedup vs baseline: 2.0071x; 2.0071x over previous
//
#include <hip/hip_runtime.h>
#include <stdint.h>

#define NB 256      // batch
#define TSEQ 1024   // sequence length
#define TT_MAX 64

// W_hh per-row split (128 f16-pairs per gate row): 28 reg + 48 LDS + 52 stream
#define REG_P 28
#define LDS_P 48
#define STR_P 52
#define LDSTR 148   // u32 stride of per-thread LDS slice (3*48=144+pad; 148%32=20 -> period-8 bank walk, 0 conflicts measured R13)

typedef _Float16 f16;
typedef _Float16 h2 __attribute__((ext_vector_type(2)));

static __device__ __forceinline__ uint32_t pkh2(float a, float b) {
  h2 v; v[0] = (f16)a; v[1] = (f16)b;
  return __builtin_bit_cast(uint32_t, v);
}

#if __has_builtin(__builtin_amdgcn_fdot2)
static __device__ __forceinline__ float dot2u(uint32_t w, uint32_t h, float c) {
  return __builtin_amdgcn_fdot2(__builtin_bit_cast(h2, w), __builtin_bit_cast(h2, h), c, false);
}
#else
static __device__ __forceinline__ float dot2u(uint32_t w, uint32_t h, float c) {
  h2 a = __builtin_bit_cast(h2, w), b = __builtin_bit_cast(h2, h);
  return c + (float)a[0] * (float)b[0] + (float)a[1] * (float)b[1];
}
#endif

#if __has_builtin(__builtin_amdgcn_rcpf)
#define RCPF(x) __builtin_amdgcn_rcpf(x)
#else
#define RCPF(x) (1.0f / (x))
#endif

static __device__ __forceinline__ float sigm(float x) {
  return RCPF(1.0f + exp2f(-1.44269504f * x));
}
static __device__ __forceinline__ float tanh_f(float x) {
  return 1.0f - 2.0f * RCPF(1.0f + exp2f(2.88539008f * x));
}

// ---------------------------------------------------------------------------
// One-time weight pack (f16). Thread t owns gate rows (t, t+256, t+512).
//  whr : reg part,    [(rr*7  + p/4)*256 + t] uint4, pairs [0,28)
//  whl : LDS part,    [t*LDSTR + rr*48 + p],         pairs [28,76)
//  whs : stream part, [(rr*13 + p/4)*256 + t] uint4, pairs [76,128)
//  whz : W_ih z-cols, [(rr*4  + p/4)*256 + t] uint4, 16 pairs
//  wep : enc h-part,  [(p/4)*256 + t] uint4 — thread t holds enc row e=t&63,
//        k-pairs pc = (t>>6)*32 + p
// ---------------------------------------------------------------------------
__global__ __launch_bounds__(256) void vrnn_pack(
    const float* __restrict__ W_hh, const float* __restrict__ W_ih,
    const float* __restrict__ emW, const float* __restrict__ esW,
    uint32_t* __restrict__ whr, uint32_t* __restrict__ whl,
    uint32_t* __restrict__ whs, uint32_t* __restrict__ whz,
    uint32_t* __restrict__ wep)
{
  const int t = threadIdx.x;
  for (int rr = 0; rr < 3; ++rr) {
    const float* R = W_hh + (size_t)(t + rr * 256) * 256;
    for (int p = 0; p < REG_P; ++p)
      whr[(((size_t)rr * 7 + (p >> 2)) * 256 + t) * 4 + (p & 3)] = pkh2(R[2 * p], R[2 * p + 1]);
    for (int p = 0; p < LDS_P; ++p)
      whl[(size_t)t * LDSTR + rr * LDS_P + p] = pkh2(R[2 * (p + REG_P)], R[2 * (p + REG_P) + 1]);
    for (int p = 0; p < STR_P; ++p)
      whs[(((size_t)rr * 13 + (p >> 2)) * 256 + t) * 4 + (p & 3)] =
          pkh2(R[2 * (p + REG_P + LDS_P)], R[2 * (p + REG_P + LDS_P) + 1]);
    const float* Z = W_ih + (size_t)(t + rr * 256) * 96 + 64;
    for (int p = 0; p < 16; ++p)
      whz[(((size_t)rr * 4 + (p >> 2)) * 256 + t) * 4 + (p & 3)] = pkh2(Z[2 * p], Z[2 * p + 1]);
  }
  const int e = t & 63, s = t >> 6;
  const float* src = (e < 32) ? (emW + (size_t)e * 320 + 64)
                              : (esW + (size_t)(e - 32) * 320 + 64);
  for (int p = 0; p < 32; ++p) {
    int pc = s * 32 + p;
    wep[(((size_t)(p >> 2)) * 256 + t) * 4 + (p & 3)] = pkh2(src[2 * pc], src[2 * pc + 1]);
  }
}

// ---------------------------------------------------------------------------
// Precompute kernel (unchanged): gi_x'[t][b][768], zx'[t][b][64]
// ---------------------------------------------------------------------------
__global__ __launch_bounds__(256, 2) void vrnn_pre(
    const float* __restrict__ x, const float* __restrict__ W_ih,
    const float* __restrict__ b_ih, const float* __restrict__ b_hh,
    const float* __restrict__ emW, const float* __restrict__ emb,
    const float* __restrict__ esW, const float* __restrict__ esb,
    f16* __restrict__ gix, f16* __restrict__ zx,
    int chunk_t0, int TT, int nTT)
{
  const int tid = threadIdx.x;
  const int b  = blockIdx.x / nTT;
  const int tt = blockIdx.x % nTT;
  const int tloc0 = tt * TT;

  uint32_t wx[3][32];
  float bias[3];
  #pragma unroll
  for (int rr = 0; rr < 3; ++rr) {
    int j = tid + rr * 256;
    const float4* wr = (const float4*)(W_ih + (size_t)j * 96);
    #pragma unroll
    for (int p4 = 0; p4 < 16; ++p4) {
      float4 v = wr[p4];
      wx[rr][2 * p4]     = pkh2(v.x, v.y);
      wx[rr][2 * p4 + 1] = pkh2(v.z, v.w);
    }
    bias[rr] = b_ih[j] + (rr < 2 ? b_hh[j] : 0.0f);  // fold b_hh into r,z rows only
  }
  uint32_t we[32]; float ebias = 0.0f;
  if (tid < 64) {
    const float* src = (tid < 32) ? (emW + (size_t)tid * 320)
                                  : (esW + (size_t)(tid - 32) * 320);
    #pragma unroll
    for (int p = 0; p < 32; ++p) we[p] = pkh2(src[2 * p], src[2 * p + 1]);
    ebias = (tid < 32) ? emb[tid] : esb[tid - 32];
  }

  __shared__ uint32_t xs[TT_MAX * 32];
  for (int idx = tid; idx < TT * 32; idx += 256) {
    int tl = idx >> 5, pk = idx & 31;
    size_t base = ((size_t)b * TSEQ + (chunk_t0 + tloc0 + tl)) * 64 + 2 * pk;
    xs[idx] = pkh2(x[base], x[base + 1]);
  }
  __syncthreads();

  for (int tl = 0; tl < TT; ++tl) {
    float a0 = bias[0], a1 = bias[1], a2 = bias[2];
    #pragma unroll
    for (int p = 0; p < 32; ++p) {
      uint32_t u = xs[tl * 32 + p];
      a0 = dot2u(wx[0][p], u, a0);
      a1 = dot2u(wx[1][p], u, a1);
      a2 = dot2u(wx[2][p], u, a2);
    }
    size_t ob = (size_t)(tloc0 + tl) * NB + b;
    f16* g = gix + ob * 768;
    g[tid] = (f16)a0; g[tid + 256] = (f16)a1; g[tid + 512] = (f16)a2;
    if (tid < 64) {
      float a3 = ebias;
      #pragma unroll
      for (int p = 0; p < 32; ++p) a3 = dot2u(we[p], xs[tl * 32 + p], a3);
      zx[ob * 64 + tid] = (f16)a3;
    }
  }
}

// ---------------------------------------------------------------------------
// Recurrent kernel v7: 256 threads, ONE batch per block (grid 256 — R13's
// 128-block layout idled half the CUs; reverted). vs R12: (a) stream chunks
// software-pipelined — rr0 of step t+1 issued in step t's phase C, rr1/rr2
// issued between LDS dot-groups, each with 70+ VALU ops of latency cover;
// sched_barrier(0) pins issue position (R10 lesson: compiler sinks loads to
// use). (b) enc weights LDS->regs (wep), LDS_P 36->48. (c) REG_P 40->28 to
// fit pinned(164)+sbuf(52)+misc under the 256-VGPR cap.
// ---------------------------------------------------------------------------
__global__ __launch_bounds__(256, 2) void vrnn_rec(
    const f16* __restrict__ gix, const f16* __restrict__ zx,
    const float* __restrict__ eps,
    const uint32_t* __restrict__ whr, const uint32_t* __restrict__ whl_g,
    const uint32_t* __restrict__ whs, const uint32_t* __restrict__ whz,
    const uint32_t* __restrict__ wep_g,
    const float* __restrict__ b_hh,
    float* __restrict__ hws, float* __restrict__ out,
    int t0, int Tlen, int first, int last)
{
  const int t = threadIdx.x;
  const int b = blockIdx.x;

  // ---- pinned register weights ----
  uint32_t wrg[3][REG_P];              // 84
  {
    const uint4* w4 = (const uint4*)whr;
    #pragma unroll
    for (int c = 0; c < 21; ++c) {
      uint4 v = w4[c * 256 + t];
      int rr = c / 7, p4 = c % 7;
      wrg[rr][4 * p4] = v.x; wrg[rr][4 * p4 + 1] = v.y;
      wrg[rr][4 * p4 + 2] = v.z; wrg[rr][4 * p4 + 3] = v.w;
    }
  }
  uint32_t wz[3][16];                  // 48
  {
    const uint4* w4 = (const uint4*)whz;
    #pragma unroll
    for (int c = 0; c < 12; ++c) {
      uint4 v = w4[c * 256 + t];
      int rr = c / 4, p4 = c % 4;
      wz[rr][4 * p4] = v.x; wz[rr][4 * p4 + 1] = v.y;
      wz[rr][4 * p4 + 2] = v.z; wz[rr][4 * p4 + 3] = v.w;
    }
  }
  uint32_t we[32];                     // 32
  {
    const uint4* w4 = (const uint4*)wep_g;
    #pragma unroll
    for (int c = 0; c < 8; ++c) {
      uint4 v = w4[c * 256 + t];
      we[4 * c] = v.x; we[4 * c + 1] = v.y; we[4 * c + 2] = v.z; we[4 * c + 3] = v.w;
    }
  }
  #pragma unroll
  for (int rr = 0; rr < 3; ++rr) {
    #pragma unroll
    for (int i = 0; i < REG_P; ++i) asm volatile("" : "+v"(wrg[rr][i]));
    #pragma unroll
    for (int i = 0; i < 16; ++i)   asm volatile("" : "+v"(wz[rr][i]));
  }
  #pragma unroll
  for (int i = 0; i < 32; ++i) asm volatile("" : "+v"(we[i]));
  const float bhn = b_hh[512 + t];

  // ---- LDS (~154 KB) ----
  __shared__ uint32_t lwh[256 * LDSTR];          // 151,552 B
  __shared__ __align__(16) f16 hf[2][256];
  __shared__ float encp[256];
  __shared__ uint32_t zu[16];

  {
    const uint4* src = (const uint4*)(whl_g + (size_t)t * LDSTR);
    uint4* dst = (uint4*)(lwh + (size_t)t * LDSTR);
    #pragma unroll
    for (int j = 0; j < LDSTR / 4; ++j) dst[j] = src[j];
  }

  float hm = first ? 0.0f : hws[b * 256 + t];
  hf[0][t] = (f16)hm;
  __syncthreads();

  // ---- stream prefetch for t=0 ----
  const f16* gp0 = gix + (size_t)b * 768;
  float pf_g0 = (float)gp0[t], pf_g1 = (float)gp0[t + 256], pf_g2 = (float)gp0[t + 512];
  float pf_zm = 0.0f, pf_zl = 0.0f, pf_ep = 0.0f;
  if (t < 32) {
    const f16* zp = zx + (size_t)b * 64;
    pf_zm = (float)zp[t]; pf_zl = (float)zp[32 + t];
    pf_ep = eps[((size_t)t0 * NB + b) * 32 + t];
  }

  const int s = t >> 6;                      // wave id (phase-A k-slice)
  const uint32_t* myl = lwh + (size_t)t * LDSTR;
  const uint4* whs4 = (const uint4*)whs;

  // ---- preload stream chunk rr=0 for step 0 ----
  uint4 sbuf[13];
  #pragma unroll
  for (int j = 0; j < 13; ++j) sbuf[j] = whs4[j * 256 + t];
  __builtin_amdgcn_sched_barrier(0);

  for (int tl = 0; tl < Tlen; ++tl) {
    const int cur = tl & 1, nxt = cur ^ 1;
    const uint32_t* hu = (const uint32_t*)&hf[cur][0];
    const uint4* hu4 = (const uint4*)hu;

    // ---- phase A: encoder partials (reg weights, wave-uniform h broadcast) ----
    float ep_ = 0.0f;
    #pragma unroll
    for (int p = 0; p < 32; ++p) {
      ep_ = dot2u(we[p], hu[s * 32 + p], ep_);
    }
    encp[t] = ep_;
    __syncthreads();  // b1

    // ---- phase B: z (32 threads) || gh (all threads) ----
    if (t < 32) {
      float mu = pf_zm, lv = pf_zl;
      #pragma unroll
      for (int ss = 0; ss < 4; ++ss) {
        mu += encp[ss * 64 + t];
        lv += encp[ss * 64 + 32 + t];
      }
      float z = mu + pf_ep * exp2f(0.72134752f * lv);   // mu + eps*exp(0.5*lv)
      ((f16*)zu)[t] = (f16)z;
    }
    float g0 = 0.0f, g1 = 0.0f, g2 = 0.0f;
    // pairs [0,28): register weights
    #pragma unroll
    for (int g4 = 0; g4 < 7; ++g4) {
      uint4 u4 = hu4[g4];
      g0 = dot2u(wrg[0][4 * g4],     u4.x, g0);
      g1 = dot2u(wrg[1][4 * g4],     u4.x, g1);
      g2 = dot2u(wrg[2][4 * g4],     u4.x, g2);
      g0 = dot2u(wrg[0][4 * g4 + 1], u4.y, g0);
      g1 = dot2u(wrg[1][4 * g4 + 1], u4.y, g1);
      g2 = dot2u(wrg[2][4 * g4 + 1], u4.y, g2);
      g0 = dot2u(wrg[0][4 * g4 + 2], u4.z, g0);
      g1 = dot2u(wrg[1][4 * g4 + 2], u4.z, g1);
      g2 = dot2u(wrg[2][4 * g4 + 2], u4.z, g2);
      g0 = dot2u(wrg[0][4 * g4 + 3], u4.w, g0);
      g1 = dot2u(wrg[1][4 * g4 + 3], u4.w, g1);
      g2 = dot2u(wrg[2][4 * g4 + 3], u4.w, g2);
    }
    // consume stream rr0 (issued last iteration / preload) -> g0; issue rr1
    {
      float a = 0.0f;
      #pragma unroll
      for (int j = 0; j < 13; ++j) {
        uint4 u4 = hu4[19 + j];
        a = dot2u(sbuf[j].x, u4.x, a);
        a = dot2u(sbuf[j].y, u4.y, a);
        a = dot2u(sbuf[j].z, u4.z, a);
        a = dot2u(sbuf[j].w, u4.w, a);
      }
      g0 += a;
    }
    #pragma unroll
    for (int j = 0; j < 13; ++j) sbuf[j] = whs4[(13 + j) * 256 + t];
    __builtin_amdgcn_sched_barrier(0);
    // pairs [28,76) first half: LDS groups 0..5
    #pragma unroll
    for (int g4 = 0; g4 < 6; ++g4) {
      uint4 u4 = hu4[7 + g4];
      uint4 w0 = *(const uint4*)(myl + 0 * LDS_P + 4 * g4);
      uint4 w1 = *(const uint4*)(myl + 1 * LDS_P + 4 * g4);
      uint4 w2 = *(const uint4*)(myl + 2 * LDS_P + 4 * g4);
      g0 = dot2u(w0.x, u4.x, g0); g1 = dot2u(w1.x, u4.x, g1); g2 = dot2u(w2.x, u4.x, g2);
      g0 = dot2u(w0.y, u4.y, g0); g1 = dot2u(w1.y, u4.y, g1); g2 = dot2u(w2.y, u4.y, g2);
      g0 = dot2u(w0.z, u4.z, g0); g1 = dot2u(w1.z, u4.z, g1); g2 = dot2u(w2.z, u4.z, g2);
      g0 = dot2u(w0.w, u4.w, g0); g1 = dot2u(w1.w, u4.w, g1); g2 = dot2u(w2.w, u4.w, g2);
    }
    // consume stream rr1 -> g1; issue rr2
    {
      float a = 0.0f;
      #pragma unroll
      for (int j = 0; j < 13; ++j) {
        uint4 u4 = hu4[19 + j];
        a = dot2u(sbuf[j].x, u4.x, a);
        a = dot2u(sbuf[j].y, u4.y, a);
        a = dot2u(sbuf[j].z, u4.z, a);
        a = dot2u(sbuf[j].w, u4.w, a);
      }
      g1 += a;
    }
    #pragma unroll
    for (int j = 0; j < 13; ++j) sbuf[j] = whs4[(26 + j) * 256 + t];
    __builtin_amdgcn_sched_barrier(0);
    // pairs [28,76) second half: LDS groups 6..11
    #pragma unroll
    for (int g4 = 6; g4 < 12; ++g4) {
      uint4 u4 = hu4[7 + g4];
      uint4 w0 = *(const uint4*)(myl + 0 * LDS_P + 4 * g4);
      uint4 w1 = *(const uint4*)(myl + 1 * LDS_P + 4 * g4);
      uint4 w2 = *(const uint4*)(myl + 2 * LDS_P + 4 * g4);
      g0 = dot2u(w0.x, u4.x, g0); g1 = dot2u(w1.x, u4.x, g1); g2 = dot2u(w2.x, u4.x, g2);
      g0 = dot2u(w0.y, u4.y, g0); g1 = dot2u(w1.y, u4.y, g1); g2 = dot2u(w2.y, u4.y, g2);
      g0 = dot2u(w0.z, u4.z, g0); g1 = dot2u(w1.z, u4.z, g1); g2 = dot2u(w2.z, u4.z, g2);
      g0 = dot2u(w0.w, u4.w, g0); g1 = dot2u(w1.w, u4.w, g1); g2 = dot2u(w2.w, u4.w, g2);
    }
    // consume stream rr2 -> g2
    {
      float a = 0.0f;
      #pragma unroll
      for (int j = 0; j < 13; ++j) {
        uint4 u4 = hu4[19 + j];
        a = dot2u(sbuf[j].x, u4.x, a);
        a = dot2u(sbuf[j].y, u4.y, a);
        a = dot2u(sbuf[j].z, u4.z, a);
        a = dot2u(sbuf[j].w, u4.w, a);
      }
      g2 += a;
    }
    __syncthreads();  // b2  (zu visible)

    // ---- phase C: gi_z from broadcast z, gates ----
    float q0 = 0.0f, q1 = 0.0f, q2 = 0.0f;
    #pragma unroll
    for (int p = 0; p < 16; ++p) {
      uint32_t u = zu[p];          // broadcast reads
      q0 = dot2u(wz[0][p], u, q0);
      q1 = dot2u(wz[1][p], u, q1);
      q2 = dot2u(wz[2][p], u, q2);
    }
    float r  = sigm(pf_g0 + g0 + q0);
    float uu = sigm(pf_g1 + g1 + q1);
    float n  = tanh_f(pf_g2 + q2 + r * (g2 + bhn));
    hm = (1.0f - uu) * n + uu * hm;
    hf[nxt][t] = (f16)hm;

    // ---- issue stream rr0 for NEXT step (covered by b3 + phase A + reg dots) ----
    #pragma unroll
    for (int j = 0; j < 13; ++j) sbuf[j] = whs4[j * 256 + t];
    __builtin_amdgcn_sched_barrier(0);

    // ---- prefetch activation streams for tl+1 ----
    int tn = (tl + 1 < Tlen) ? tl + 1 : tl;
    const f16* gp = gix + ((size_t)tn * NB + b) * 768;
    pf_g0 = (float)gp[t]; pf_g1 = (float)gp[t + 256]; pf_g2 = (float)gp[t + 512];
    if (t < 32) {
      const f16* zp = zx + ((size_t)tn * NB + b) * 64;
      pf_zm = (float)zp[t]; pf_zl = (float)zp[32 + t];
      pf_ep = eps[((size_t)(t0 + tn) * NB + b) * 32 + t];
    }
    __syncthreads();  // b3  (h_new visible)
  }

  if (last) out[b * 256 + t] = hm;
  else      hws[b * 256 + t] = hm;
}

extern "C" void kernel_launch(void* const* d_in, const int* in_sizes, int n_in,
                              void* d_out, int out_size, void* d_ws, size_t ws_size,
                              hipStream_t stream) {
  const float* x    = (const float*)d_in[0];
  const float* eps  = (const float*)d_in[1];
  const float* emW  = (const float*)d_in[2];
  const float* emb  = (const float*)d_in[3];
  const float* esW  = (const float*)d_in[4];
  const float* esb  = (const float*)d_in[5];
  const float* W_ih = (const float*)d_in[10];
  const float* W_hh = (const float*)d_in[11];
  const float* b_ih = (const float*)d_in[12];
  const float* b_hh = (const float*)d_in[13];
  float* out = (float*)d_out;

  // workspace layout (16B-aligned regions)
  const size_t o_whr = 262144;                  // hws: 256 KB
  const size_t o_whl = o_whr + 86016;           // whr: 21*256*16
  const size_t o_whs = o_whl + 151552;          // whl: 148*256*4
  const size_t o_whz = o_whs + 159744;          // whs: 39*256*16
  const size_t o_wep = o_whz + 49152;           // whz: 12*256*16
  const size_t o_gix = o_wep + 32768;           // wep: 8*256*16  -> 741,376
  int Tc = TSEQ;
  while (Tc > 8 && o_gix + (size_t)Tc * NB * (768 + 64) * 2 > ws_size) Tc >>= 1;

  float*    hws   = (float*)d_ws;
  uint32_t* whr   = (uint32_t*)((char*)d_ws + o_whr);
  uint32_t* whl_g = (uint32_t*)((char*)d_ws + o_whl);
  uint32_t* whs   = (uint32_t*)((char*)d_ws + o_whs);
  uint32_t* whz   = (uint32_t*)((char*)d_ws + o_whz);
  uint32_t* wep   = (uint32_t*)((char*)d_ws + o_wep);
  f16*      gix   = (f16*)((char*)d_ws + o_gix);
  f16*      zx    = gix + (size_t)Tc * NB * 768;

  vrnn_pack<<<dim3(1), dim3(256), 0, stream>>>(W_hh, W_ih, emW, esW,
                                               whr, whl_g, whs, whz, wep);

  int nch = TSEQ / Tc;
  int TT  = Tc < 64 ? Tc : 64;
  int nTT = Tc / TT;

  for (int c = 0; c < nch; ++c) {
    vrnn_pre<<<dim3(NB * nTT), dim3(256), 0, stream>>>(
        x, W_ih, b_ih, b_hh, emW, emb, esW, esb, gix, zx, c * Tc, TT, nTT);
    vrnn_rec<<<dim3(NB), dim3(256), 0, stream>>>(
        gix, zx, eps, whr, whl_g, whs, whz, wep, b_hh, hws, out,
        c * Tc, Tc, c == 0 ? 1 : 0, c == nch - 1 ? 1 : 0);
  }
}